// Round 6
// baseline (203.332 us; speedup 1.0000x reference)
//
#include <hip/hip_runtime.h>

#define DIM 128
#define BINSHIFT 7
#define BINSZ 128          // nodes per bin
#define BCAP 2560          // edges capacity per bin: Poisson(2048)+11sigma
#define EPB 8192           // edges per binning block
#define NSL 8              // channel slices (one per XCD)
#define SC 16              // channels per slice

typedef __attribute__((ext_vector_type(8))) short bf16x8;
typedef __attribute__((ext_vector_type(4))) float f32x4;

__device__ inline unsigned short f2b(float f) {
    unsigned u = __builtin_bit_cast(unsigned, f);
    unsigned r = (u + 0x7FFFu + ((u >> 16) & 1u)) >> 16;
    return (unsigned short)r;
}
__device__ inline float b2f(unsigned short h) {
    unsigned u = ((unsigned)h) << 16;
    return __builtin_bit_cast(float, u);
}

// ---------------------------------------------------------------- x (fp32, row-major) -> xbs (bf16, slice-major [8][N][16])
__global__ __launch_bounds__(256)
void x_to_slices(const float* __restrict__ x, unsigned short* __restrict__ xbs, int N)
{
    int t = blockIdx.x * 256 + threadIdx.x;
    if (t >= N * NSL) return;
    int node = t >> 3, s = t & 7;
    const float* xp = x + (size_t)node * DIM + s * SC;
    float4 a = *(const float4*)(xp + 0);
    float4 b = *(const float4*)(xp + 4);
    float4 c = *(const float4*)(xp + 8);
    float4 d = *(const float4*)(xp + 12);
    unsigned short* o = xbs + ((size_t)s * N + node) * SC;
    bf16x8 o0, o1;
    o0[0]=(short)f2b(a.x); o0[1]=(short)f2b(a.y); o0[2]=(short)f2b(a.z); o0[3]=(short)f2b(a.w);
    o0[4]=(short)f2b(b.x); o0[5]=(short)f2b(b.y); o0[6]=(short)f2b(b.z); o0[7]=(short)f2b(b.w);
    o1[0]=(short)f2b(c.x); o1[1]=(short)f2b(c.y); o1[2]=(short)f2b(c.z); o1[3]=(short)f2b(c.w);
    o1[4]=(short)f2b(d.x); o1[5]=(short)f2b(d.y); o1[6]=(short)f2b(d.z); o1[7]=(short)f2b(d.w);
    *(bf16x8*)(o + 0) = o0;
    *(bf16x8*)(o + 8) = o1;
}

// ---------------------------------------------------------------- bin edges by dst>>7, packed (dstlow<<17)|src ; gcur starts at 0
__global__ __launch_bounds__(1024)
void bin_edges(const int* __restrict__ src, const int* __restrict__ dst,
               unsigned* __restrict__ gcur, unsigned* __restrict__ binned,
               int E, int nbins)
{
    __shared__ unsigned hist[1024];
    __shared__ unsigned base[1024];
    const int t = threadIdx.x;
    const long long bb = (long long)blockIdx.x * EPB;
    if (t < nbins) hist[t] = 0;
    __syncthreads();

    unsigned pk[8], pos[8];
    int bn[8];
    bool ok[8];
    #pragma unroll
    for (int i = 0; i < 8; ++i) {
        long long idx = bb + i * 1024 + t;
        ok[i] = idx < E;
        if (ok[i]) {
            int s = src[idx], d = dst[idx];
            pk[i] = ((unsigned)(d & (BINSZ - 1)) << 17) | (unsigned)s;
            bn[i] = d >> BINSHIFT;
            pos[i] = atomicAdd(&hist[bn[i]], 1u);
        }
    }
    __syncthreads();
    if (t < nbins) base[t] = (unsigned)t * BCAP + atomicAdd(&gcur[t], hist[t]);
    __syncthreads();
    #pragma unroll
    for (int i = 0; i < 8; ++i) {
        if (ok[i]) {
            unsigned off = base[bn[i]] + pos[i];
            if (off < (unsigned)(bn[i] + 1) * BCAP) binned[off] = pk[i];
        }
    }
}

// ---------------------------------------------------------------- per-bin counting sort -> srt (src grouped by node) + per-node base/cnt
__global__ __launch_bounds__(512)
void bin_sort(const unsigned* __restrict__ gcur, const unsigned* __restrict__ binned,
              unsigned* __restrict__ srt, unsigned* __restrict__ gbase,
              unsigned* __restrict__ ghist)
{
    __shared__ unsigned hist[BINSZ];
    __shared__ unsigned base[BINSZ];
    __shared__ unsigned cur[BINSZ];
    const int t = threadIdx.x;
    const int bin = blockIdx.x;

    if (t < BINSZ) hist[t] = 0;
    __syncthreads();

    int cnt = (int)gcur[bin];
    if (cnt > BCAP) cnt = BCAP;
    const unsigned* __restrict__ bp = binned + (size_t)bin * BCAP;

    for (int i = t; i < cnt; i += 512)
        atomicAdd(&hist[(bp[i] >> 17) & (BINSZ - 1)], 1u);
    __syncthreads();
    if (t == 0) {
        unsigned run = 0;
        for (int i = 0; i < BINSZ; ++i) { base[i] = run; run += hist[i]; }
    }
    __syncthreads();
    if (t < BINSZ) cur[t] = base[t];
    __syncthreads();
    unsigned* __restrict__ sp = srt + (size_t)bin * BCAP;
    for (int i = t; i < cnt; i += 512) {
        unsigned p = bp[i];
        unsigned pos = atomicAdd(&cur[(p >> 17) & (BINSZ - 1)], 1u);
        sp[pos] = p & 0x1FFFFu;
    }
    if (t < BINSZ) {
        gbase[bin * BINSZ + t] = base[t];
        ghist[bin * BINSZ + t] = hist[t];
    }
}

// ---------------------------------------------------------------- channel-sliced gather: block = (bin, slice); slice -> XCD via blockIdx&7
// 256 threads: 2 lanes per node (8 ch each), 128 nodes per bin
__global__ __launch_bounds__(256)
void gather_slice(const unsigned short* __restrict__ xbs, const float* __restrict__ epsp,
                  const unsigned* __restrict__ gcur, const unsigned* __restrict__ srt,
                  const unsigned* __restrict__ gbase, const unsigned* __restrict__ ghist,
                  unsigned short* __restrict__ h0b, int N)
{
    __shared__ unsigned ssrt[BCAP];     // 10 KB
    __shared__ unsigned sbase[BINSZ];
    __shared__ unsigned shist[BINSZ];
    const int t = threadIdx.x;
    const int bin = blockIdx.x >> 3;
    const int slice = blockIdx.x & 7;
    const int node0 = bin << BINSHIFT;

    int cnt = (int)gcur[bin];
    if (cnt > BCAP) cnt = BCAP;
    const unsigned* __restrict__ sp = srt + (size_t)bin * BCAP;
    for (int i = t; i < cnt; i += 256) ssrt[i] = sp[i];
    if (t < BINSZ) {
        sbase[t] = gbase[bin * BINSZ + t];
        shist[t] = ghist[bin * BINSZ + t];
    }
    __syncthreads();

    const float e = 1.0f + epsp[0];
    const int dn = t >> 1;              // node in bin
    const int c8 = (t & 1) * 8;         // 8-channel half of the slice
    const int node = node0 + dn;
    if (node >= N) return;

    const unsigned short* __restrict__ xs = xbs + (size_t)slice * N * SC + c8;
    bf16x8 v0 = *(const bf16x8*)(xs + (size_t)node * SC);
    float acc[8];
    #pragma unroll
    for (int q = 0; q < 8; ++q) acc[q] = e * b2f((unsigned short)v0[q]);

    const int b0 = (int)sbase[dn], hn = (int)shist[dn];
    int j = 0;
    for (; j + 4 <= hn; j += 4) {
        unsigned s0 = ssrt[b0 + j + 0];
        unsigned s1 = ssrt[b0 + j + 1];
        unsigned s2 = ssrt[b0 + j + 2];
        unsigned s3 = ssrt[b0 + j + 3];
        bf16x8 r0 = *(const bf16x8*)(xs + (size_t)s0 * SC);
        bf16x8 r1 = *(const bf16x8*)(xs + (size_t)s1 * SC);
        bf16x8 r2 = *(const bf16x8*)(xs + (size_t)s2 * SC);
        bf16x8 r3 = *(const bf16x8*)(xs + (size_t)s3 * SC);
        #pragma unroll
        for (int q = 0; q < 8; ++q)
            acc[q] += b2f((unsigned short)r0[q]) + b2f((unsigned short)r1[q])
                    + b2f((unsigned short)r2[q]) + b2f((unsigned short)r3[q]);
    }
    for (; j < hn; ++j) {
        unsigned s0 = ssrt[b0 + j];
        bf16x8 r0 = *(const bf16x8*)(xs + (size_t)s0 * SC);
        #pragma unroll
        for (int q = 0; q < 8; ++q) acc[q] += b2f((unsigned short)r0[q]);
    }
    bf16x8 o;
    #pragma unroll
    for (int q = 0; q < 8; ++q) o[q] = (short)f2b(acc[q]);
    *(bf16x8*)(h0b + (size_t)node * DIM + slice * SC + c8) = o;
}

// ---------------------------------------------------------------- MFMA GEMM + bias + BN-stats (+optional input BN+ReLU)
template<bool APPLY_BN, bool OUT_BF16>
__global__ __launch_bounds__(1024)
void gemm_mfma(const unsigned short* __restrict__ A, const float* __restrict__ Wf,
               const float* __restrict__ bias, const float* __restrict__ ss,
               void* __restrict__ outp, float* __restrict__ stats, int N)
{
    __shared__ unsigned short sWT[128 * 128];  // swizzled W^T (bf16), 32 KB
    __shared__ float red[256];
    const int tid = threadIdx.x;

    #pragma unroll
    for (int i = 0; i < 4; ++i) {
        int idx = (i * 1024 + tid) * 4;
        float4 w = *(const float4*)&Wf[idx];
        int k = idx >> 7, n0 = idx & 127;
        sWT[(n0 + 0) * 128 + (k ^ (((n0 + 0) & 7) << 3))] = f2b(w.x);
        sWT[(n0 + 1) * 128 + (k ^ (((n0 + 1) & 7) << 3))] = f2b(w.y);
        sWT[(n0 + 2) * 128 + (k ^ (((n0 + 2) & 7) << 3))] = f2b(w.z);
        sWT[(n0 + 3) * 128 + (k ^ (((n0 + 3) & 7) << 3))] = f2b(w.w);
    }
    if (tid < 256) red[tid] = 0.f;
    __syncthreads();

    const int lane = tid & 63;
    const int wave = tid >> 6;
    const int r0   = blockIdx.x * 256 + wave * 16;
    const int rl   = lane & 15;
    const int kg   = lane >> 4;
    int rr = r0 + rl;
    int rclamp = rr < N ? rr : N - 1;
    const unsigned short* arow = A + (size_t)rclamp * DIM + kg * 8;

    f32x4 acc[8];
    #pragma unroll
    for (int nt = 0; nt < 8; ++nt) acc[nt] = (f32x4)(0.f);

    #pragma unroll
    for (int kk = 0; kk < 128; kk += 32) {
        bf16x8 a8 = *(const bf16x8*)(arow + kk);
        if (APPLY_BN) {
            const float* sc = ss + kk + kg * 8;
            const float* sh = sc + DIM;
            bf16x8 tt;
            #pragma unroll
            for (int j = 0; j < 8; ++j) {
                float f = b2f((unsigned short)a8[j]) * sc[j] + sh[j];
                tt[j] = (short)f2b(fmaxf(f, 0.f));
            }
            a8 = tt;
        }
        const int ks = kk + kg * 8;
        #pragma unroll
        for (int nt = 0; nt < 8; ++nt) {
            int n = nt * 16 + rl;
            bf16x8 b8 = *(const bf16x8*)&sWT[n * 128 + (ks ^ ((n & 7) << 3))];
            acc[nt] = __builtin_amdgcn_mfma_f32_16x16x32_bf16(a8, b8, acc[nt], 0, 0, 0);
        }
    }

    const int orow0 = r0 + kg * 4;
    #pragma unroll
    for (int nt = 0; nt < 8; ++nt) {
        int n = nt * 16 + rl;
        float bb = bias[n];
        float ls = 0.f, ls2 = 0.f;
        #pragma unroll
        for (int j = 0; j < 4; ++j) {
            int r = orow0 + j;
            if (r < N) {
                float v = acc[nt][j] + bb;
                if (OUT_BF16) ((unsigned short*)outp)[(size_t)r * DIM + n] = f2b(v);
                else          ((float*)outp)[(size_t)r * DIM + n] = v;
                ls += v; ls2 += v * v;
            }
        }
        ls  += __shfl_xor(ls, 16);  ls  += __shfl_xor(ls, 32);
        ls2 += __shfl_xor(ls2, 16); ls2 += __shfl_xor(ls2, 32);
        if (kg == 0) { atomicAdd(&red[n], ls); atomicAdd(&red[128 + n], ls2); }
    }
    __syncthreads();
    if (tid < 256) atomicAdd(&stats[tid], red[tid]);
}

// ---------------------------------------------------------------- BN finalize
__global__ void bn_finalize(const float* __restrict__ stats, const float* __restrict__ gamma,
                            const float* __restrict__ beta, float* __restrict__ ss, float invN)
{
    int c = threadIdx.x;
    float mu  = stats[c] * invN;
    float var = stats[DIM + c] * invN - mu * mu;
    var = fmaxf(var, 0.f);
    float sc = gamma[c] * rsqrtf(var + 1e-5f);
    ss[c]       = sc;
    ss[DIM + c] = beta[c] - mu * sc;
}

// ---------------------------------------------------------------- final BN+ReLU: bf16 h2 -> fp32 out
__global__ __launch_bounds__(256)
void bn_relu_out_b(const unsigned short* __restrict__ h2b, const float* __restrict__ ss,
                   float* __restrict__ out, int n8)
{
    int i = blockIdx.x * 256 + threadIdx.x;
    if (i >= n8) return;
    int c = (i * 8) & 127;
    bf16x8 v = *(const bf16x8*)(h2b + (size_t)i * 8);
    float4 o0, o1;
    o0.x = fmaxf(b2f((unsigned short)v[0]) * ss[c+0] + ss[DIM+c+0], 0.f);
    o0.y = fmaxf(b2f((unsigned short)v[1]) * ss[c+1] + ss[DIM+c+1], 0.f);
    o0.z = fmaxf(b2f((unsigned short)v[2]) * ss[c+2] + ss[DIM+c+2], 0.f);
    o0.w = fmaxf(b2f((unsigned short)v[3]) * ss[c+3] + ss[DIM+c+3], 0.f);
    o1.x = fmaxf(b2f((unsigned short)v[4]) * ss[c+4] + ss[DIM+c+4], 0.f);
    o1.y = fmaxf(b2f((unsigned short)v[5]) * ss[c+5] + ss[DIM+c+5], 0.f);
    o1.z = fmaxf(b2f((unsigned short)v[6]) * ss[c+6] + ss[DIM+c+6], 0.f);
    o1.w = fmaxf(b2f((unsigned short)v[7]) * ss[c+7] + ss[DIM+c+7], 0.f);
    ((float4*)out)[i * 2 + 0] = o0;
    ((float4*)out)[i * 2 + 1] = o1;
}

// ----------------------------------------------------------------
extern "C" void kernel_launch(void* const* d_in, const int* in_sizes, int n_in,
                              void* d_out, int out_size, void* d_ws, size_t ws_size,
                              hipStream_t stream) {
    const float* x    = (const float*)d_in[0];
    const int*   ei   = (const int*)  d_in[1];
    const float* W1   = (const float*)d_in[2];
    const float* b1   = (const float*)d_in[3];
    const float* g1   = (const float*)d_in[4];
    const float* be1  = (const float*)d_in[5];
    const float* W2   = (const float*)d_in[6];
    const float* b2   = (const float*)d_in[7];
    const float* g2   = (const float*)d_in[8];
    const float* be2  = (const float*)d_in[9];
    const float* epsp = (const float*)d_in[10];
    float* out = (float*)d_out;

    const int N = in_sizes[0] / DIM;   // 100000
    const int E = in_sizes[1] / 2;     // 1600000
    const int* src = ei;
    const int* dst = ei + E;
    const int nbins = (N + BINSZ - 1) >> BINSHIFT;   // 782

    // workspace layout (~68 MB, overlaid):
    //   [0]        xbs  [8][N][16] bf16 (25.6 MB)   -> h1b overlays (xbs dead after gather_slice)
    //   [SZ]       h0b  [N][128]  bf16 (25.6 MB)    -> h2b overlays (h0b dead after gemm1)
    //   [2SZ]      binned [nbins*BCAP u32] (8.0 MB)
    //   [..]       srt    [nbins*BCAP u32] (8.0 MB)
    //   [..]       gbase/ghist [nbins*128 u32 each] (0.8 MB)
    //   [..]       gcur[1024 u32] | stats1[256] | stats2[256] | ss1[256] | ss2[256]
    const size_t SZ = (size_t)N * DIM * sizeof(unsigned short);
    char* w = (char*)d_ws;
    unsigned short* xbs = (unsigned short*)w;
    unsigned short* h1b = xbs;
    unsigned short* h0b = (unsigned short*)(w + SZ);
    unsigned short* h2b = h0b;
    unsigned* binned = (unsigned*)(w + 2 * SZ);
    unsigned* srt    = binned + (size_t)nbins * BCAP;
    unsigned* gbase  = srt + (size_t)nbins * BCAP;
    unsigned* ghist  = gbase + (size_t)nbins * BINSZ;
    unsigned* gcur   = ghist + (size_t)nbins * BINSZ;
    float* stats1 = (float*)(gcur + 1024);
    float* stats2 = stats1 + 256;
    float* ss1    = stats2 + 256;
    float* ss2    = ss1 + 256;

    // zero gcur + stats1 + stats2 in one shot (contiguous)
    hipMemsetAsync(gcur, 0, (1024 + 512) * sizeof(unsigned), stream);

    x_to_slices<<<(N * NSL + 255) / 256, 256, 0, stream>>>(x, xbs, N);
    bin_edges<<<(E + EPB - 1) / EPB, 1024, 0, stream>>>(src, dst, gcur, binned, E, nbins);
    bin_sort<<<nbins, 512, 0, stream>>>(gcur, binned, srt, gbase, ghist);
    gather_slice<<<nbins * NSL, 256, 0, stream>>>(xbs, epsp, gcur, srt, gbase, ghist, h0b, N);

    const int gblocks = (N + 255) / 256;
    gemm_mfma<false, true><<<gblocks, 1024, 0, stream>>>(h0b, W1, b1, nullptr, h1b, stats1, N);
    bn_finalize<<<1, DIM, 0, stream>>>(stats1, g1, be1, ss1, 1.0f / (float)N);
    gemm_mfma<true, true><<<gblocks, 1024, 0, stream>>>(h1b, W2, b2, ss1, h2b, stats2, N);
    bn_finalize<<<1, DIM, 0, stream>>>(stats2, g2, be2, ss2, 1.0f / (float)N);
    const int n8 = N * DIM / 8;
    bn_relu_out_b<<<(n8 + 255) / 256, 256, 0, stream>>>(h2b, ss2, out, n8);
}

// Round 7
// 187.649 us; speedup vs baseline: 1.0836x; 1.0836x over previous
//
#include <hip/hip_runtime.h>

#define DIM 128
#define BINSHIFT 7
#define BINSZ 128          // nodes per bin
#define BCAP 2560          // edges capacity per bin: Poisson(2048)+11sigma
#define EPB 8192           // edges per binning block

typedef __attribute__((ext_vector_type(8))) short bf16x8;
typedef __attribute__((ext_vector_type(4))) float f32x4;

__device__ inline unsigned short f2b(float f) {
    unsigned u = __builtin_bit_cast(unsigned, f);
    unsigned r = (u + 0x7FFFu + ((u >> 16) & 1u)) >> 16;
    return (unsigned short)r;
}
__device__ inline float b2f(unsigned short h) {
    unsigned u = ((unsigned)h) << 16;
    return __builtin_bit_cast(float, u);
}

// ---------------------------------------------------------------- x (fp32) -> xb (bf16, row-major)
__global__ __launch_bounds__(256)
void x_to_bf16(const float* __restrict__ x, unsigned short* __restrict__ xb, int n8)
{
    int i = blockIdx.x * 256 + threadIdx.x;
    if (i >= n8) return;
    float4 a = ((const float4*)x)[i * 2];
    float4 b = ((const float4*)x)[i * 2 + 1];
    bf16x8 o;
    o[0] = (short)f2b(a.x); o[1] = (short)f2b(a.y); o[2] = (short)f2b(a.z); o[3] = (short)f2b(a.w);
    o[4] = (short)f2b(b.x); o[5] = (short)f2b(b.y); o[6] = (short)f2b(b.z); o[7] = (short)f2b(b.w);
    ((bf16x8*)xb)[i] = o;
}

// ---------------------------------------------------------------- bin edges by dst>>7, packed (dstlow<<17)|src ; gcur starts at 0
__global__ __launch_bounds__(1024)
void bin_edges(const int* __restrict__ src, const int* __restrict__ dst,
               unsigned* __restrict__ gcur, unsigned* __restrict__ binned,
               int E, int nbins)
{
    __shared__ unsigned hist[1024];
    __shared__ unsigned base[1024];
    const int t = threadIdx.x;
    const long long bb = (long long)blockIdx.x * EPB;
    if (t < nbins) hist[t] = 0;
    __syncthreads();

    unsigned pk[8], pos[8];
    int bn[8];
    bool ok[8];
    #pragma unroll
    for (int i = 0; i < 8; ++i) {
        long long idx = bb + i * 1024 + t;
        ok[i] = idx < E;
        if (ok[i]) {
            int s = src[idx], d = dst[idx];
            pk[i] = ((unsigned)(d & (BINSZ - 1)) << 17) | (unsigned)s;
            bn[i] = d >> BINSHIFT;
            pos[i] = atomicAdd(&hist[bn[i]], 1u);
        }
    }
    __syncthreads();
    if (t < nbins) base[t] = (unsigned)t * BCAP + atomicAdd(&gcur[t], hist[t]);
    __syncthreads();
    #pragma unroll
    for (int i = 0; i < 8; ++i) {
        if (ok[i]) {
            unsigned off = base[bn[i]] + pos[i];
            if (off < (unsigned)(bn[i] + 1) * BCAP) binned[off] = pk[i];
        }
    }
}

// ---------------------------------------------------------------- per-bin counting sort -> srt (src grouped by node) + per-node base/cnt
__global__ __launch_bounds__(512)
void bin_sort(const unsigned* __restrict__ gcur, const unsigned* __restrict__ binned,
              unsigned* __restrict__ srt, unsigned* __restrict__ gbase,
              unsigned* __restrict__ ghist)
{
    __shared__ unsigned hist[BINSZ];
    __shared__ unsigned base[BINSZ];
    __shared__ unsigned cur[BINSZ];
    const int t = threadIdx.x;
    const int bin = blockIdx.x;

    if (t < BINSZ) hist[t] = 0;
    __syncthreads();

    int cnt = (int)gcur[bin];
    if (cnt > BCAP) cnt = BCAP;
    const unsigned* __restrict__ bp = binned + (size_t)bin * BCAP;

    for (int i = t; i < cnt; i += 512)
        atomicAdd(&hist[(bp[i] >> 17) & (BINSZ - 1)], 1u);
    __syncthreads();
    if (t == 0) {
        unsigned run = 0;
        for (int i = 0; i < BINSZ; ++i) { base[i] = run; run += hist[i]; }
    }
    __syncthreads();
    if (t < BINSZ) cur[t] = base[t];
    __syncthreads();
    unsigned* __restrict__ sp = srt + (size_t)bin * BCAP;
    for (int i = t; i < cnt; i += 512) {
        unsigned p = bp[i];
        unsigned pos = atomicAdd(&cur[(p >> 17) & (BINSZ - 1)], 1u);
        sp[pos] = p & 0x1FFFFu;
    }
    if (t < BINSZ) {
        gbase[bin * BINSZ + t] = base[t];   // indexed by node id
        ghist[bin * BINSZ + t] = hist[t];
    }
}

// ---------------------------------------------------------------- CSR gather: 32 nodes/block, 16 lanes/node x 8 ch, no LDS
__global__ __launch_bounds__(512)
void gather_csr(const unsigned short* __restrict__ xb, const float* __restrict__ epsp,
                const unsigned* __restrict__ srt, const unsigned* __restrict__ gbase,
                const unsigned* __restrict__ ghist,
                unsigned short* __restrict__ h0b, int N)
{
    const int t = threadIdx.x;
    const int node = blockIdx.x * 32 + (t >> 4);
    if (node >= N) return;
    const int g = (t & 15) * 8;
    const float e = 1.0f + epsp[0];

    bf16x8 v0 = *(const bf16x8*)(xb + (size_t)node * DIM + g);
    float acc[8];
    #pragma unroll
    for (int q = 0; q < 8; ++q) acc[q] = e * b2f((unsigned short)v0[q]);

    const int b0 = (int)gbase[node];
    const int hn = (int)ghist[node];
    const unsigned* __restrict__ sp = srt + (size_t)(node >> BINSHIFT) * BCAP + b0;

    int j = 0;
    for (; j + 4 <= hn; j += 4) {
        unsigned s0 = sp[j + 0];
        unsigned s1 = sp[j + 1];
        unsigned s2 = sp[j + 2];
        unsigned s3 = sp[j + 3];
        bf16x8 r0 = *(const bf16x8*)(xb + (size_t)s0 * DIM + g);
        bf16x8 r1 = *(const bf16x8*)(xb + (size_t)s1 * DIM + g);
        bf16x8 r2 = *(const bf16x8*)(xb + (size_t)s2 * DIM + g);
        bf16x8 r3 = *(const bf16x8*)(xb + (size_t)s3 * DIM + g);
        #pragma unroll
        for (int q = 0; q < 8; ++q)
            acc[q] += b2f((unsigned short)r0[q]) + b2f((unsigned short)r1[q])
                    + b2f((unsigned short)r2[q]) + b2f((unsigned short)r3[q]);
    }
    for (; j < hn; ++j) {
        unsigned s0 = sp[j];
        bf16x8 r0 = *(const bf16x8*)(xb + (size_t)s0 * DIM + g);
        #pragma unroll
        for (int q = 0; q < 8; ++q) acc[q] += b2f((unsigned short)r0[q]);
    }
    bf16x8 o;
    #pragma unroll
    for (int q = 0; q < 8; ++q) o[q] = (short)f2b(acc[q]);
    *(bf16x8*)(h0b + (size_t)node * DIM + g) = o;
}

// ---------------------------------------------------------------- MFMA GEMM + bias + BN-stats (+optional input BN+ReLU)
template<bool APPLY_BN, bool OUT_BF16>
__global__ __launch_bounds__(1024)
void gemm_mfma(const unsigned short* __restrict__ A, const float* __restrict__ Wf,
               const float* __restrict__ bias, const float* __restrict__ ss,
               void* __restrict__ outp, float* __restrict__ stats, int N)
{
    __shared__ unsigned short sWT[128 * 128];  // swizzled W^T (bf16), 32 KB
    __shared__ float red[256];
    const int tid = threadIdx.x;

    #pragma unroll
    for (int i = 0; i < 4; ++i) {
        int idx = (i * 1024 + tid) * 4;
        float4 w = *(const float4*)&Wf[idx];
        int k = idx >> 7, n0 = idx & 127;
        sWT[(n0 + 0) * 128 + (k ^ (((n0 + 0) & 7) << 3))] = f2b(w.x);
        sWT[(n0 + 1) * 128 + (k ^ (((n0 + 1) & 7) << 3))] = f2b(w.y);
        sWT[(n0 + 2) * 128 + (k ^ (((n0 + 2) & 7) << 3))] = f2b(w.z);
        sWT[(n0 + 3) * 128 + (k ^ (((n0 + 3) & 7) << 3))] = f2b(w.w);
    }
    if (tid < 256) red[tid] = 0.f;
    __syncthreads();

    const int lane = tid & 63;
    const int wave = tid >> 6;
    const int r0   = blockIdx.x * 256 + wave * 16;
    const int rl   = lane & 15;
    const int kg   = lane >> 4;
    int rr = r0 + rl;
    int rclamp = rr < N ? rr : N - 1;
    const unsigned short* arow = A + (size_t)rclamp * DIM + kg * 8;

    f32x4 acc[8];
    #pragma unroll
    for (int nt = 0; nt < 8; ++nt) acc[nt] = (f32x4)(0.f);

    #pragma unroll
    for (int kk = 0; kk < 128; kk += 32) {
        bf16x8 a8 = *(const bf16x8*)(arow + kk);
        if (APPLY_BN) {
            const float* sc = ss + kk + kg * 8;
            const float* sh = sc + DIM;
            bf16x8 tt;
            #pragma unroll
            for (int j = 0; j < 8; ++j) {
                float f = b2f((unsigned short)a8[j]) * sc[j] + sh[j];
                tt[j] = (short)f2b(fmaxf(f, 0.f));
            }
            a8 = tt;
        }
        const int ks = kk + kg * 8;
        #pragma unroll
        for (int nt = 0; nt < 8; ++nt) {
            int n = nt * 16 + rl;
            bf16x8 b8 = *(const bf16x8*)&sWT[n * 128 + (ks ^ ((n & 7) << 3))];
            acc[nt] = __builtin_amdgcn_mfma_f32_16x16x32_bf16(a8, b8, acc[nt], 0, 0, 0);
        }
    }

    const int orow0 = r0 + kg * 4;
    #pragma unroll
    for (int nt = 0; nt < 8; ++nt) {
        int n = nt * 16 + rl;
        float bb = bias[n];
        float ls = 0.f, ls2 = 0.f;
        #pragma unroll
        for (int j = 0; j < 4; ++j) {
            int r = orow0 + j;
            if (r < N) {
                float v = acc[nt][j] + bb;
                if (OUT_BF16) ((unsigned short*)outp)[(size_t)r * DIM + n] = f2b(v);
                else          ((float*)outp)[(size_t)r * DIM + n] = v;
                ls += v; ls2 += v * v;
            }
        }
        ls  += __shfl_xor(ls, 16);  ls  += __shfl_xor(ls, 32);
        ls2 += __shfl_xor(ls2, 16); ls2 += __shfl_xor(ls2, 32);
        if (kg == 0) { atomicAdd(&red[n], ls); atomicAdd(&red[128 + n], ls2); }
    }
    __syncthreads();
    if (tid < 256) atomicAdd(&stats[tid], red[tid]);
}

// ---------------------------------------------------------------- BN finalize
__global__ void bn_finalize(const float* __restrict__ stats, const float* __restrict__ gamma,
                            const float* __restrict__ beta, float* __restrict__ ss, float invN)
{
    int c = threadIdx.x;
    float mu  = stats[c] * invN;
    float var = stats[DIM + c] * invN - mu * mu;
    var = fmaxf(var, 0.f);
    float sc = gamma[c] * rsqrtf(var + 1e-5f);
    ss[c]       = sc;
    ss[DIM + c] = beta[c] - mu * sc;
}

// ---------------------------------------------------------------- final BN+ReLU: bf16 h2 -> fp32 out
__global__ __launch_bounds__(256)
void bn_relu_out_b(const unsigned short* __restrict__ h2b, const float* __restrict__ ss,
                   float* __restrict__ out, int n8)
{
    int i = blockIdx.x * 256 + threadIdx.x;
    if (i >= n8) return;
    int c = (i * 8) & 127;
    bf16x8 v = *(const bf16x8*)(h2b + (size_t)i * 8);
    float4 o0, o1;
    o0.x = fmaxf(b2f((unsigned short)v[0]) * ss[c+0] + ss[DIM+c+0], 0.f);
    o0.y = fmaxf(b2f((unsigned short)v[1]) * ss[c+1] + ss[DIM+c+1], 0.f);
    o0.z = fmaxf(b2f((unsigned short)v[2]) * ss[c+2] + ss[DIM+c+2], 0.f);
    o0.w = fmaxf(b2f((unsigned short)v[3]) * ss[c+3] + ss[DIM+c+3], 0.f);
    o1.x = fmaxf(b2f((unsigned short)v[4]) * ss[c+4] + ss[DIM+c+4], 0.f);
    o1.y = fmaxf(b2f((unsigned short)v[5]) * ss[c+5] + ss[DIM+c+5], 0.f);
    o1.z = fmaxf(b2f((unsigned short)v[6]) * ss[c+6] + ss[DIM+c+6], 0.f);
    o1.w = fmaxf(b2f((unsigned short)v[7]) * ss[c+7] + ss[DIM+c+7], 0.f);
    ((float4*)out)[i * 2 + 0] = o0;
    ((float4*)out)[i * 2 + 1] = o1;
}

// ----------------------------------------------------------------
extern "C" void kernel_launch(void* const* d_in, const int* in_sizes, int n_in,
                              void* d_out, int out_size, void* d_ws, size_t ws_size,
                              hipStream_t stream) {
    const float* x    = (const float*)d_in[0];
    const int*   ei   = (const int*)  d_in[1];
    const float* W1   = (const float*)d_in[2];
    const float* b1   = (const float*)d_in[3];
    const float* g1   = (const float*)d_in[4];
    const float* be1  = (const float*)d_in[5];
    const float* W2   = (const float*)d_in[6];
    const float* b2   = (const float*)d_in[7];
    const float* g2   = (const float*)d_in[8];
    const float* be2  = (const float*)d_in[9];
    const float* epsp = (const float*)d_in[10];
    float* out = (float*)d_out;

    const int N = in_sizes[0] / DIM;   // 100000
    const int E = in_sizes[1] / 2;     // 1600000
    const int* src = ei;
    const int* dst = ei + E;
    const int nbins = (N + BINSZ - 1) >> BINSHIFT;   // 782

    // workspace layout (~76.8 MB + tail):
    //   [0]     xb  [N*128 ushort]  25.6 MB
    //   [SZ]    h0b [N*128 ushort]  25.6 MB   (h2b overlays: h0b dead after gemm1)
    //   [2SZ]   regC (25.6 MB): binned(8) | srt(8) | gbase(.4) | ghist(.4) | pad
    //           h1b overlays regC (binned/srt/gbase/ghist dead before h1b written)
    //   [3SZ]   tail: gcur[1024 u32] | stats1[256] | stats2[256] | ss1[256] | ss2[256]
    const size_t SZ = (size_t)N * DIM * sizeof(unsigned short);
    char* w = (char*)d_ws;
    unsigned short* xb  = (unsigned short*)w;
    unsigned short* h0b = (unsigned short*)(w + SZ);
    unsigned short* h2b = h0b;
    unsigned short* h1b = (unsigned short*)(w + 2 * SZ);
    unsigned* binned = (unsigned*)(w + 2 * SZ);
    unsigned* srt    = binned + (size_t)nbins * BCAP;
    unsigned* gbase  = srt + (size_t)nbins * BCAP;
    unsigned* ghist  = gbase + (size_t)nbins * BINSZ;
    unsigned* gcur   = (unsigned*)(w + 3 * SZ);
    float* stats1 = (float*)(gcur + 1024);
    float* stats2 = stats1 + 256;
    float* ss1    = stats2 + 256;
    float* ss2    = ss1 + 256;

    // zero gcur + stats1 + stats2 (contiguous)
    hipMemsetAsync(gcur, 0, (1024 + 512) * sizeof(unsigned), stream);

    const int n8 = N * DIM / 8;
    x_to_bf16<<<(n8 + 255) / 256, 256, 0, stream>>>(x, xb, n8);
    bin_edges<<<(E + EPB - 1) / EPB, 1024, 0, stream>>>(src, dst, gcur, binned, E, nbins);
    bin_sort<<<nbins, 512, 0, stream>>>(gcur, binned, srt, gbase, ghist);
    gather_csr<<<(N + 31) / 32, 512, 0, stream>>>(xb, epsp, srt, gbase, ghist, h0b, N);

    const int gblocks = (N + 255) / 256;
    gemm_mfma<false, true><<<gblocks, 1024, 0, stream>>>(h0b, W1, b1, nullptr, h1b, stats1, N);
    bn_finalize<<<1, DIM, 0, stream>>>(stats1, g1, be1, ss1, 1.0f / (float)N);
    gemm_mfma<true, true><<<gblocks, 1024, 0, stream>>>(h1b, W2, b2, ss1, h2b, stats2, N);
    bn_finalize<<<1, DIM, 0, stream>>>(stats2, g2, be2, ss2, 1.0f / (float)N);
    bn_relu_out_b<<<(n8 + 255) / 256, 256, 0, stream>>>(h2b, ss2, out, n8);
}